// Round 16
// baseline (287.301 us; speedup 1.0000x reference)
//
#include <hip/hip_runtime.h>
#include <hip/hip_bf16.h>
#include <math.h>

typedef __hip_bfloat16 bf16;
typedef __bf16 bf16x4 __attribute__((ext_vector_type(4)));
typedef __bf16 bf16x8 __attribute__((ext_vector_type(8)));
typedef float f32x4 __attribute__((ext_vector_type(4)));
typedef float f32x16 __attribute__((ext_vector_type(16)));
typedef unsigned short us4 __attribute__((ext_vector_type(4)));

#define LOG2E 1.44269504088896340736f

#if defined(__has_builtin)
#if __has_builtin(__builtin_amdgcn_exp2f)
#define EXP2(x) __builtin_amdgcn_exp2f(x)
#else
#define EXP2(x) exp2f(x)
#endif
#else
#define EXP2(x) exp2f(x)
#endif

// Session-measured rules:
// - __launch_bounds__ arg2 caps VGPRs at ~256/arg2; cap < live set => spill.
// - reg-staged LDS tiles are DS-op issue-bound; async16 deletes writes (r8).
// - attn occupancy halves at the 64-VGPR step (r8/r10/r11).
// - XCD-aware block swizzle (r12): attn FETCH 71->12.6 MB, dur 73->60.
// - attn is DS-issue-bound (r13 analysis). This round: K AND V fragments are
//   per-lane-private rows of L2-resident arrays -> read BOTH direct from
//   global. No K/V LDS staging, no per-tile barriers at all; LDS = merge
//   buffer only (35840 B -> 4 blocks/CU; TLP hides the L2 load latency).

__device__ inline __bf16 f2b(float f) {
  __hip_bfloat16 h = __float2bfloat16(f);
  return *reinterpret_cast<__bf16*>(&h);
}
__device__ inline unsigned short b2u(float f) {  // RNE (cold paths)
  __hip_bfloat16 h = __float2bfloat16(f);
  return *reinterpret_cast<unsigned short*>(&h);
}
__device__ inline unsigned short b2u_fast(float f) {  // round-half-up (hot loop)
  union { float f; unsigned u; } v;
  v.f = f;
  return (unsigned short)((v.u + 0x8000u) >> 16);
}
__device__ inline us4 shfl32_us4(us4 v) {
  uint2 u = *(uint2*)&v;
  u.x = __shfl_xor(u.x, 32);
  u.y = __shfl_xor(u.y, 32);
  return *(us4*)&u;
}
__device__ inline bf16x8 mk8(us4 lo, us4 hi) {
  bf16x4 l = *(bf16x4*)&lo;
  bf16x4 h = *(bf16x4*)&hi;
  return __builtin_shufflevector(l, h, 0, 1, 2, 3, 4, 5, 6, 7);
}
// async global->LDS, 16B/lane, lds addr = wave-uniform base + lane*16
__device__ inline void async16(const bf16* g, bf16* l) {
  __builtin_amdgcn_global_load_lds(
      (const __attribute__((address_space(1))) unsigned int*)g,
      (__attribute__((address_space(3))) unsigned int*)l, 16, 0, 0);
}

// ---------------- prep: weight transpose+cast (z<3) + T5 bias LUT (z==3)
// ---------------- + input fp32->bf16 cast (z=4,5)
__global__ void prep_k(const float* __restrict__ Wq, const float* __restrict__ Wkv,
                       const float* __restrict__ Wo, const float* __restrict__ rel_bias,
                       const float* __restrict__ hidden, const float* __restrict__ kvs,
                       bf16* __restrict__ WqT, bf16* __restrict__ WkvT,
                       bf16* __restrict__ WoT, float* __restrict__ lut,
                       bf16* __restrict__ hbf, bf16* __restrict__ kbf) {
  __shared__ float tile[32][33];
  int z = blockIdx.z;
  int tx = threadIdx.x, ty = threadIdx.y;
  if (z >= 4) {  // input cast: 2 slices x 2048 blocks x 2048 f32 each
    int bidFlat = (z - 4) * 2048 + blockIdx.y * 64 + blockIdx.x;  // 0..4095
    int gid = bidFlat * 256 + ty * 32 + tx;
    const float* in = (gid < 524288) ? hidden : kvs;
    bf16* out = (gid < 524288) ? hbf : kbf;
    int i = (gid & 524287) * 8;
    float4 a0 = *(const float4*)(in + i);
    float4 a1 = *(const float4*)(in + i + 4);
    bf16x8 v;
    v[0] = f2b(a0.x); v[1] = f2b(a0.y); v[2] = f2b(a0.z); v[3] = f2b(a0.w);
    v[4] = f2b(a1.x); v[5] = f2b(a1.y); v[6] = f2b(a1.z); v[7] = f2b(a1.w);
    *(bf16x8*)(out + i) = v;
    return;
  }
  if (z == 3) {  // T5 bias LUT (f64 bucketing = np ref), pre-scaled by log2e
    if (blockIdx.y != 0 || blockIdx.x >= 16) return;
    int r = blockIdx.x * 256 + ty * 32 + tx;
    int rel = r - 2048;
    int bkt = rel > 0 ? 16 : 0;
    int ar = rel < 0 ? -rel : rel;
    int idx;
    if (ar < 8) {
      idx = bkt + ar;
    } else {
      double t = log((double)ar / 8.0) / log(16.0) * 8.0;
      int lg = 8 + (int)t;
      if (lg > 15) lg = 15;
      idx = bkt + lg;
    }
    for (int h = 0; h < 16; ++h)
      lut[h * 4096 + r] = rel_bias[idx * 16 + h] * LOG2E;
    return;
  }
  const float* in = z == 0 ? Wq : (z == 1 ? Wkv : Wo);
  bf16* out = z == 0 ? WqT : (z == 1 ? WkvT : WoT);
  int cols = z == 1 ? 2048 : 1024;
  int c0 = blockIdx.x * 32;
  if (c0 >= cols) return;
  int r0 = blockIdx.y * 32;
  for (int i = ty; i < 32; i += 8)
    tile[i][tx] = in[(size_t)(r0 + i) * cols + c0 + tx];
  __syncthreads();
  for (int i = ty; i < 32; i += 8)
    out[(size_t)(c0 + i) * 1024 + r0 + tx] = __float2bfloat16(tile[tx][i]);
}

// ---------------- fused Q+KV projection GEMM (pure async16, r13-verified) ----------------
// 1D grid 768, XCD-swizzled: by = xcd*3 + slot>>5, bx = slot&31.
// by<8 -> Q (x log2e) -> Qb[b,h,s,d]; by>=8: gn<1024 -> Kb, gn>=1024 -> Vt.
__global__ __launch_bounds__(256) void gemm_qkv_k(const bf16* __restrict__ hbf,
                                                  const bf16* __restrict__ kbf,
                                                  const bf16* __restrict__ WqT,
                                                  const bf16* __restrict__ WkvT,
                                                  bf16* __restrict__ Qb,
                                                  bf16* __restrict__ Kb,
                                                  bf16* __restrict__ Vt) {
  __shared__ __align__(16) bf16 As[128 * 32];
  __shared__ __align__(16) bf16 Bs[128 * 32];
  const int tid = threadIdx.x;
  const int lane = tid & 63;
  const int w = tid >> 6;
  const int wm = (w >> 1) * 64;
  const int wn = (w & 1) * 64;
  const int l15 = lane & 15;
  const int quad = lane >> 4;
  const int srow = lane >> 2;
  const int skg = lane & 3;

  const int wg = blockIdx.x;            // 0..767
  const int xcd = wg & 7;
  const int slot = wg >> 3;             // 0..95
  const int by = xcd * 3 + (slot >> 5); // 0..23
  const int bx = slot & 31;             // 0..31

  const bool isQ = by < 8;
  const bf16* A = isQ ? hbf : kbf;
  const bf16* Bt = isQ ? WqT : WkvT;
  const int n0 = (isQ ? by : by - 8) * 128;
  const int m0 = bx * 128;
  const bool isV = (!isQ) && (n0 >= 1024);

  f32x4 acc[4][4];
#pragma unroll
  for (int i = 0; i < 4; ++i)
#pragma unroll
    for (int j = 0; j < 4; ++j) acc[i][j] = (f32x4){0.f, 0.f, 0.f, 0.f};

  for (int k0 = 0; k0 < 1024; k0 += 32) {
    __syncthreads();
#pragma unroll
    for (int rep = 0; rep < 2; ++rep) {
      int seg = w * 2 + rep;
      async16(A + (size_t)(m0 + seg * 16 + srow) * 1024 + k0 + skg * 8, As + seg * 512);
      async16(Bt + (size_t)(n0 + seg * 16 + srow) * 1024 + k0 + skg * 8, Bs + seg * 512);
    }
    __syncthreads();
    bf16x8 af[4], bfr[4];
#pragma unroll
    for (int i = 0; i < 4; ++i)
      af[i] = *(const bf16x8*)(As + (wm + i * 16 + l15) * 32 + quad * 8);
#pragma unroll
    for (int j = 0; j < 4; ++j)
      bfr[j] = *(const bf16x8*)(Bs + (wn + j * 16 + l15) * 32 + quad * 8);
    if (isV) {  // normal: lane regs vary gm (=k of V) for packed V^T store
#pragma unroll
      for (int i = 0; i < 4; ++i)
#pragma unroll
        for (int j = 0; j < 4; ++j)
          acc[i][j] = __builtin_amdgcn_mfma_f32_16x16x32_bf16(af[i], bfr[j], acc[i][j], 0, 0, 0);
    } else {  // swapped: D^T, lane regs vary gn (=d) for packed Q/K store
#pragma unroll
      for (int i = 0; i < 4; ++i)
#pragma unroll
        for (int j = 0; j < 4; ++j)
          acc[i][j] = __builtin_amdgcn_mfma_f32_16x16x32_bf16(bfr[j], af[i], acc[i][j], 0, 0, 0);
    }
  }

  if (isV) {  // V -> [b,h,d,k], 4 consecutive k per 8B store
#pragma unroll
    for (int i = 0; i < 4; ++i) {
      int gmb = m0 + wm + i * 16 + quad * 4;
      int b = gmb >> 11, kp = gmb & 2047;
#pragma unroll
      for (int j = 0; j < 4; ++j) {
        int gn = n0 + wn + j * 16 + l15;
        int h = (gn >> 6) & 15, d = gn & 63;
        us4 pk;
#pragma unroll
        for (int r = 0; r < 4; ++r) pk[r] = b2u(acc[i][j][r]);
        *(us4*)(Vt + ((((size_t)b * 16 + h) * 64 + d) << 11) + kp) = pk;
      }
    }
    return;
  }
  // Q/K swapped epilogue: gm = ..+l15 (s), gn = ..+quad*4+r (d packed)
  const float scale = isQ ? LOG2E : 1.0f;
  bf16* dst = isQ ? Qb : Kb;
#pragma unroll
  for (int i = 0; i < 4; ++i) {
    int gm = m0 + wm + i * 16 + l15;
    int b = gm >> 11, s = gm & 2047;
#pragma unroll
    for (int j = 0; j < 4; ++j) {
      int gn = n0 + wn + j * 16 + quad * 4;
      int h = (gn >> 6) & 15, d0 = gn & 63;
      us4 pk;
#pragma unroll
      for (int r = 0; r < 4; ++r) pk[r] = b2u(acc[i][j][r] * scale);
      *(us4*)(dst + ((((size_t)b * 16 + h) * 2048 + s) << 6) + d0) = pk;
    }
  }
}

// ---------------- O projection: out[4096][1024] = Ob * WoT^T, 128x64 tiles ----------------
// 1D grid 512, XCD-swizzled; pure async16 (r13-verified)
__global__ __launch_bounds__(256) void gemm_o_k(const bf16* __restrict__ A,
                                                const bf16* __restrict__ Bt,
                                                float* __restrict__ C0) {
  __shared__ __align__(16) bf16 As[128 * 32];
  __shared__ __align__(16) bf16 Bs[64 * 32];
  const int tid = threadIdx.x;
  const int lane = tid & 63;
  const int w = tid >> 6;
  const int wm = w * 32;

  const int wg = blockIdx.x;            // 0..511
  const int xcd = wg & 7;
  const int slot = wg >> 3;             // 0..63
  const int by = xcd * 2 + (slot >> 5); // 0..15
  const int bx = slot & 31;             // 0..31
  const int m0 = bx * 128;
  const int n0 = by * 64;

  const int l15 = lane & 15;
  const int quad = lane >> 4;
  const int srow = lane >> 2;
  const int skg = lane & 3;

  f32x4 acc[2][4];
#pragma unroll
  for (int i = 0; i < 2; ++i)
#pragma unroll
    for (int j = 0; j < 4; ++j) acc[i][j] = (f32x4){0.f, 0.f, 0.f, 0.f};

  for (int k0 = 0; k0 < 1024; k0 += 32) {
    __syncthreads();
#pragma unroll
    for (int rep = 0; rep < 2; ++rep) {
      int seg = w * 2 + rep;
      async16(A + (size_t)(m0 + seg * 16 + srow) * 1024 + k0 + skg * 8, As + seg * 512);
    }
    async16(Bt + (size_t)(n0 + w * 16 + srow) * 1024 + k0 + skg * 8, Bs + w * 512);
    __syncthreads();
    bf16x8 af[2], bfr[4];
#pragma unroll
    for (int i = 0; i < 2; ++i)
      af[i] = *(const bf16x8*)(As + (wm + i * 16 + l15) * 32 + quad * 8);
#pragma unroll
    for (int j = 0; j < 4; ++j)
      bfr[j] = *(const bf16x8*)(Bs + (j * 16 + l15) * 32 + quad * 8);
#pragma unroll
    for (int i = 0; i < 2; ++i)
#pragma unroll
      for (int j = 0; j < 4; ++j)
        acc[i][j] = __builtin_amdgcn_mfma_f32_16x16x32_bf16(bfr[j], af[i], acc[i][j], 0, 0, 0);
  }
#pragma unroll
  for (int i = 0; i < 2; ++i) {
    int gm = m0 + wm + i * 16 + l15;
#pragma unroll
    for (int j = 0; j < 4; ++j) {
      int gn = n0 + j * 16 + quad * 4;
      *(f32x4*)(C0 + (size_t)gm * 1024 + gn) = acc[i][j];
    }
  }
}

// ---------------- fused attention: NO K/V LDS staging, NO in-loop barriers ----------------
// K and V fragments are both per-lane-private (K row = kt+mt*32+q31;
// V row = dj*32+q31) and L2-resident per XCD (r12 swizzle). Read both DIRECT
// from global -- zero staging DS ops, zero per-tile barriers. LDS holds only
// lbias (8704 B, loop) + merge buffer (35840 B, overlay after loop) ->
// 4 blocks/CU by LDS; TLP hides L2 latency.
// 8 waves / 512 threads: waves 0-3 (kg=0) even 128-k tiles, waves 4-7 odd.
// Softmax FIXED m=0 (scores bounded ~|25|; exact for any consistent m).
// Group 1 dumps (l,O) to LDS; group 0 merges: O=(O0+O1)/(l0+l1).
__global__ __launch_bounds__(512, 2) void attn_k(const bf16* __restrict__ Qb,
                                                 const bf16* __restrict__ Kb,
                                                 const bf16* __restrict__ Vt,
                                                 const float* __restrict__ lut,
                                                 bf16* __restrict__ Ob) {
  __shared__ __align__(16) char smem[35840];
  float* lbias = (float*)smem;

  const int tid = threadIdx.x;
  const int lane = tid & 63;
  const int w = tid >> 6;    // 0..7
  const int wq = w & 3;      // q-strip within block
  const int kg = w >> 2;     // k-group: 0 = even tiles, 1 = odd tiles
  const int q31 = lane & 31;
  const int half = lane >> 5;

  // XCD swizzle: wg = xcd + 8*slot (HW round-robin wg->XCD assumption)
  const int wg = blockIdx.x;        // 0..511
  const int xcd = wg & 7;
  const int slot = wg >> 3;         // 0..63
  const int bh = xcd * 4 + (slot >> 4);  // 0..31
  const int qt = slot & 15;              // 0..15
  const int h = bh & 15, b = bh >> 4;
  const int qb = qt * 128;

  const int gbase = h * 4096 + 1921 - qb;
  for (int t = tid; t < 2175; t += 512) lbias[t] = lut[gbase + t];

  const size_t base = (size_t)bh * 2048 * 64;   // Qb/Kb rows
  const size_t vbase = (size_t)bh * 64 * 2048;  // Vt rows
  const int qg = qb + wq * 32 + q31;

  // per-lane K row pointer (row = q31 within each 32-k chunk)
  const bf16* kptr = Kb + base + (size_t)q31 * 64 + half * 8;
  // per-lane V row pointers (rows d = dj*32 + q31 of Vt)
  const bf16* vptr0 = Vt + vbase + (size_t)q31 * 2048 + half * 8;
  const bf16* vptr1 = vptr0 + 32 * 2048;

  // Q B-frags (pre-scaled by log2e in projection)
  bf16x8 qf[4];
#pragma unroll
  for (int c = 0; c < 4; ++c)
    qf[c] = *(const bf16x8*)(Qb + base + (size_t)qg * 64 + c * 16 + half * 8);

  f32x16 oacc[2];
#pragma unroll
  for (int dj = 0; dj < 2; ++dj)
#pragma unroll
    for (int r = 0; r < 16; ++r) oacc[dj][r] = 0.f;
  float l_run = 0.f;

  __syncthreads();  // lbias visible to all waves

  const int kt0 = kg * 128;  // group's first tile

  for (int it = 0; it < 8; ++it) {
    const int kt = it * 256 + kt0;  // this group's k-tile base
    const int xbase = kt + 127 + 4 * half - wq * 32 - q31;
#pragma unroll
    for (int mt = 0; mt < 4; ++mt) {
      // S^T = K·Q^T for this 32-k mt-tile; bias pre-loaded in the accumulator.
      const bf16* kmt = kptr + (size_t)(kt + mt * 32) * 64;
      f32x16 sacc;
#pragma unroll
      for (int a2 = 0; a2 < 4; ++a2)
#pragma unroll
        for (int rr = 0; rr < 4; ++rr)
          sacc[4 * a2 + rr] = lbias[xbase + mt * 32 + 8 * a2 + rr];
#pragma unroll
      for (int c = 0; c < 4; ++c) {
        bf16x8 kf = *(const bf16x8*)(kmt + c * 16);
        sacc = __builtin_amdgcn_mfma_f32_32x32x16_bf16(kf, qf[c], sacc, 0, 0, 0);
      }

      // exp (m=0, no subtract) + sum (4 parallel accumulators) + pack quads
      us4 ownq[4];
      f32x4 sv = (f32x4){0.f, 0.f, 0.f, 0.f};
#pragma unroll
      for (int a = 0; a < 4; ++a) {
        us4 pk;
#pragma unroll
        for (int rr = 0; rr < 4; ++rr) {
          float p = EXP2(sacc[4 * a + rr]);
          sv[rr] += p;
          pk[rr] = b2u_fast(p);
        }
        ownq[a] = pk;
      }
      l_run += (sv[0] + sv[1]) + (sv[2] + sv[3]);

      // exchange complementary k-quads across the half boundary (no LDS)
      us4 rcv0 = shfl32_us4(half ? ownq[0] : ownq[1]);
      us4 rcv1 = shfl32_us4(half ? ownq[2] : ownq[3]);

      // O^T += V^T·P^T; V frags DIRECT from global (per-lane rows, L2-hot)
#pragma unroll
      for (int p = 0; p < 2; ++p) {
        us4 rc = p ? rcv1 : rcv0;
        bf16x8 pfc = half ? mk8(rc, ownq[2 * p + 1]) : mk8(ownq[2 * p], rc);
        int kcol = kt + (mt * 2 + p) * 16;
        bf16x8 vf0 = *(const bf16x8*)(vptr0 + kcol);
        oacc[0] = __builtin_amdgcn_mfma_f32_32x32x16_bf16(vf0, pfc, oacc[0], 0, 0, 0);
        bf16x8 vf1 = *(const bf16x8*)(vptr1 + kcol);
        oacc[1] = __builtin_amdgcn_mfma_f32_32x32x16_bf16(vf1, pfc, oacc[1], 0, 0, 0);
      }
    }
  }

  // pair-sum of l (one shfl at the end)
  l_run += __shfl_xor(l_run, 32);

  // ---- merge the two k-groups (group 1 -> LDS -> group 0 combines) ----
  __syncthreads();  // all waves done with lbias; smem reused as merge buffer
  float* mbuf = (float*)smem;  // 4 waves * 64 lanes * 35 f32 = 35840 B
  if (kg) {
    float* p = mbuf + ((size_t)(wq * 64 + lane)) * 35;  // stride 35: 2-way banks, free
    p[0] = l_run;
#pragma unroll
    for (int dj = 0; dj < 2; ++dj)
#pragma unroll
      for (int r = 0; r < 16; ++r) p[1 + dj * 16 + r] = oacc[dj][r];
  }
  __syncthreads();
  if (kg) return;

  const float* p = mbuf + ((size_t)(wq * 64 + lane)) * 35;
  float inv = 1.0f / (l_run + p[0]);

  // epilogue: O[qg][d] = (O0+O1)/(l0+l1), 8B packed stores
#pragma unroll
  for (int dj = 0; dj < 2; ++dj)
#pragma unroll
    for (int g = 0; g < 4; ++g) {
      us4 pk;
#pragma unroll
      for (int rr = 0; rr < 4; ++rr)
        pk[rr] = b2u((oacc[dj][4 * g + rr] + p[1 + dj * 16 + 4 * g + rr]) * inv);
      int d0 = dj * 32 + 8 * g + 4 * half;
      *(us4*)(Ob + ((size_t)(b * 2048 + qg)) * 1024 + h * 64 + d0) = pk;
    }
}

// ---------------- launch ----------------
extern "C" void kernel_launch(void* const* d_in, const int* in_sizes, int n_in,
                              void* d_out, int out_size, void* d_ws, size_t ws_size,
                              hipStream_t stream) {
  const float* hidden = (const float*)d_in[0];
  const float* kvs    = (const float*)d_in[1];
  const float* Wq     = (const float*)d_in[2];
  const float* Wkv    = (const float*)d_in[3];
  const float* Wo     = (const float*)d_in[4];
  const float* relb   = (const float*)d_in[5];
  float* out = (float*)d_out;

  char* ws = (char*)d_ws;
  bf16* WqT  = (bf16*)(ws + (size_t)0);           // 2 MB
  bf16* WkvT = (bf16*)(ws + ((size_t)2 << 20));   // 4 MB
  bf16* WoT  = (bf16*)(ws + ((size_t)6 << 20));   // 2 MB
  bf16* Ob   = (bf16*)(ws + ((size_t)8 << 20));   // 8 MB [B,S,E]
  bf16* hbf  = Ob;                                //   aliased: dead after gemm_qkv
  bf16* Qb   = (bf16*)(ws + ((size_t)16 << 20));  // 8 MB [B,H,S,D]
  bf16* Kb   = (bf16*)(ws + ((size_t)24 << 20));  // 8 MB [B,H,K,D]
  bf16* Vt   = (bf16*)(ws + ((size_t)32 << 20));  // 8 MB [B,H,D,K]
  float* LUT = (float*)(ws + ((size_t)40 << 20)); // 256 KB
  bf16* kbf  = (bf16*)d_out;                      // 8 MB scratch in d_out, overwritten by gemm_o

  // weights transpose+cast + bias LUT + input cast, ONE launch (z=0..5)
  prep_k<<<dim3(64, 32, 6), dim3(32, 8), 0, stream>>>(Wq, Wkv, Wo, relb, hidden, kvs,
                                                      WqT, WkvT, WoT, LUT, hbf, kbf);
  // Q (x log2e), K, V projections; 1D grid, XCD-swizzled
  gemm_qkv_k<<<dim3(768), 256, 0, stream>>>(hbf, kbf, WqT, WkvT, Qb, Kb, Vt);
  // attention -> Ob (overwrites hbf region, safe: hbf consumed); XCD-swizzled
  attn_k<<<dim3(512), 512, 0, stream>>>(Qb, Kb, Vt, LUT, Ob);
  // out = Ob @ Wo (overwrites kbf region, safe: kbf consumed); XCD-swizzled
  gemm_o_k<<<dim3(512), 256, 0, stream>>>(Ob, WoT, out);
}

// Round 17
// 218.633 us; speedup vs baseline: 1.3141x; 1.3141x over previous
//
#include <hip/hip_runtime.h>
#include <hip/hip_bf16.h>
#include <math.h>

typedef __hip_bfloat16 bf16;
typedef __bf16 bf16x4 __attribute__((ext_vector_type(4)));
typedef __bf16 bf16x8 __attribute__((ext_vector_type(8)));
typedef float f32x4 __attribute__((ext_vector_type(4)));
typedef float f32x16 __attribute__((ext_vector_type(16)));
typedef unsigned short us4 __attribute__((ext_vector_type(4)));

#define LOG2E 1.44269504088896340736f

#if defined(__has_builtin)
#if __has_builtin(__builtin_amdgcn_exp2f)
#define EXP2(x) __builtin_amdgcn_exp2f(x)
#else
#define EXP2(x) exp2f(x)
#endif
#else
#define EXP2(x) exp2f(x)
#endif

// Session-measured rules (final):
// - __launch_bounds__ arg2 caps VGPRs at ~256/arg2; cap < live set => spill.
// - async16 staging beats reg-staging for bf16 linear layouts (r8).
// - attn occupancy halves at the 64-VGPR step; features costing >4 VGPR past
//   60 are net-negative (r10 prefetch -8%, r11 sat-bias -13%).
// - XCD-aware block swizzle (r12): attn FETCH 71->12.6 MB, dur 73->60.
// - LDS K/V staging is LATENCY AMORTIZATION, not overhead: direct-from-global
//   K/V (r16) put ~200cyc L2 latency on every MFMA chain -> 2.2x regression
//   despite highest-ever occupancy. Keep the bulk-staged structure.

__device__ inline __bf16 f2b(float f) {
  __hip_bfloat16 h = __float2bfloat16(f);
  return *reinterpret_cast<__bf16*>(&h);
}
__device__ inline unsigned short b2u(float f) {  // RNE (cold paths)
  __hip_bfloat16 h = __float2bfloat16(f);
  return *reinterpret_cast<unsigned short*>(&h);
}
__device__ inline unsigned short b2u_fast(float f) {  // round-half-up (hot loop)
  union { float f; unsigned u; } v;
  v.f = f;
  return (unsigned short)((v.u + 0x8000u) >> 16);
}
// 16B logical LDS read as two 8B reads (2-way-bank-friendly padded strides)
__device__ inline bf16x8 ld16(const bf16* p) {
  bf16x4 lo = *(const bf16x4*)p;
  bf16x4 hi = *(const bf16x4*)(p + 4);
  return __builtin_shufflevector(lo, hi, 0, 1, 2, 3, 4, 5, 6, 7);
}
__device__ inline void st16(bf16* p, uint4 v) {
  *(uint2*)p = make_uint2(v.x, v.y);
  *(uint2*)(p + 4) = make_uint2(v.z, v.w);
}
__device__ inline us4 shfl32_us4(us4 v) {
  uint2 u = *(uint2*)&v;
  u.x = __shfl_xor(u.x, 32);
  u.y = __shfl_xor(u.y, 32);
  return *(us4*)&u;
}
__device__ inline bf16x8 mk8(us4 lo, us4 hi) {
  bf16x4 l = *(bf16x4*)&lo;
  bf16x4 h = *(bf16x4*)&hi;
  return __builtin_shufflevector(l, h, 0, 1, 2, 3, 4, 5, 6, 7);
}
// async global->LDS, 16B/lane, lds addr = wave-uniform base + lane*16
__device__ inline void async16(const bf16* g, bf16* l) {
  __builtin_amdgcn_global_load_lds(
      (const __attribute__((address_space(1))) unsigned int*)g,
      (__attribute__((address_space(3))) unsigned int*)l, 16, 0, 0);
}

// ---------------- fused fp32 -> bf16 cast for hidden+kvs ----------------
__global__ void cast2_k(const float* __restrict__ a, const float* __restrict__ b,
                        bf16* __restrict__ oa, bf16* __restrict__ ob) {
  int gid = blockIdx.x * 256 + threadIdx.x;  // grid 4096 blocks
  const float* in = (gid < 524288) ? a : b;
  bf16* out = (gid < 524288) ? oa : ob;
  int i = (gid & 524287) * 8;
  float4 a0 = *(const float4*)(in + i);
  float4 a1 = *(const float4*)(in + i + 4);
  bf16x8 v;
  v[0] = f2b(a0.x); v[1] = f2b(a0.y); v[2] = f2b(a0.z); v[3] = f2b(a0.w);
  v[4] = f2b(a1.x); v[5] = f2b(a1.y); v[6] = f2b(a1.z); v[7] = f2b(a1.w);
  *(bf16x8*)(out + i) = v;
}

// ---------------- prep: weight transpose+cast (z<3) + T5 bias LUT (z==3) ----------------
__global__ void prep_k(const float* __restrict__ Wq, const float* __restrict__ Wkv,
                       const float* __restrict__ Wo, const float* __restrict__ rel_bias,
                       bf16* __restrict__ WqT, bf16* __restrict__ WkvT,
                       bf16* __restrict__ WoT, float* __restrict__ lut) {
  __shared__ float tile[32][33];
  int z = blockIdx.z;
  int tx = threadIdx.x, ty = threadIdx.y;
  if (z == 3) {  // T5 bias LUT (f64 bucketing = np ref), pre-scaled by log2e
    if (blockIdx.y != 0 || blockIdx.x >= 16) return;
    int r = blockIdx.x * 256 + ty * 32 + tx;
    int rel = r - 2048;
    int bkt = rel > 0 ? 16 : 0;
    int ar = rel < 0 ? -rel : rel;
    int idx;
    if (ar < 8) {
      idx = bkt + ar;
    } else {
      double t = log((double)ar / 8.0) / log(16.0) * 8.0;
      int lg = 8 + (int)t;
      if (lg > 15) lg = 15;
      idx = bkt + lg;
    }
    for (int h = 0; h < 16; ++h)
      lut[h * 4096 + r] = rel_bias[idx * 16 + h] * LOG2E;
    return;
  }
  const float* in = z == 0 ? Wq : (z == 1 ? Wkv : Wo);
  bf16* out = z == 0 ? WqT : (z == 1 ? WkvT : WoT);
  int cols = z == 1 ? 2048 : 1024;
  int c0 = blockIdx.x * 32;
  if (c0 >= cols) return;
  int r0 = blockIdx.y * 32;
  for (int i = ty; i < 32; i += 8)
    tile[i][tx] = in[(size_t)(r0 + i) * cols + c0 + tx];
  __syncthreads();
  for (int i = ty; i < 32; i += 8)
    out[(size_t)(c0 + i) * 1024 + r0 + tx] = __float2bfloat16(tile[tx][i]);
}

// ---------------- fused Q+KV projection GEMM (pure async16, verified r0-r3/r10/r12) ----------------
// grid (32, 24): y<8 -> Q (x log2e) -> Qb[b,h,s,d]; y>=8: gn<1024 -> Kb[b,h,k,d],
// gn>=1024 -> Vt[b,h,d,k]. Q/K use swapped-operand MFMA (D^T) for packed epilogue.
__global__ __launch_bounds__(256) void gemm_qkv_k(const bf16* __restrict__ hbf,
                                                  const bf16* __restrict__ kbf,
                                                  const bf16* __restrict__ WqT,
                                                  const bf16* __restrict__ WkvT,
                                                  bf16* __restrict__ Qb,
                                                  bf16* __restrict__ Kb,
                                                  bf16* __restrict__ Vt) {
  __shared__ __align__(16) bf16 As[128 * 32];
  __shared__ __align__(16) bf16 Bs[128 * 32];
  const int tid = threadIdx.x;
  const int lane = tid & 63;
  const int w = tid >> 6;
  const int wm = (w >> 1) * 64;
  const int wn = (w & 1) * 64;
  const int l15 = lane & 15;
  const int quad = lane >> 4;
  const int srow = lane >> 2;
  const int skg = lane & 3;

  const bool isQ = blockIdx.y < 8;
  const bf16* A = isQ ? hbf : kbf;
  const bf16* Bt = isQ ? WqT : WkvT;
  const int n0 = (isQ ? blockIdx.y : blockIdx.y - 8) * 128;
  const int m0 = blockIdx.x * 128;
  const bool isV = (!isQ) && (n0 >= 1024);

  f32x4 acc[4][4];
#pragma unroll
  for (int i = 0; i < 4; ++i)
#pragma unroll
    for (int j = 0; j < 4; ++j) acc[i][j] = (f32x4){0.f, 0.f, 0.f, 0.f};

  for (int k0 = 0; k0 < 1024; k0 += 32) {
    __syncthreads();
#pragma unroll
    for (int rep = 0; rep < 2; ++rep) {
      int seg = w * 2 + rep;
      async16(A + (size_t)(m0 + seg * 16 + srow) * 1024 + k0 + skg * 8, As + seg * 512);
      async16(Bt + (size_t)(n0 + seg * 16 + srow) * 1024 + k0 + skg * 8, Bs + seg * 512);
    }
    __syncthreads();
    bf16x8 af[4], bfr[4];
#pragma unroll
    for (int i = 0; i < 4; ++i)
      af[i] = *(const bf16x8*)(As + (wm + i * 16 + l15) * 32 + quad * 8);
#pragma unroll
    for (int j = 0; j < 4; ++j)
      bfr[j] = *(const bf16x8*)(Bs + (wn + j * 16 + l15) * 32 + quad * 8);
    if (isV) {  // normal: lane regs vary gm (=k of V) for packed V^T store
#pragma unroll
      for (int i = 0; i < 4; ++i)
#pragma unroll
        for (int j = 0; j < 4; ++j)
          acc[i][j] = __builtin_amdgcn_mfma_f32_16x16x32_bf16(af[i], bfr[j], acc[i][j], 0, 0, 0);
    } else {  // swapped: D^T, lane regs vary gn (=d) for packed Q/K store
#pragma unroll
      for (int i = 0; i < 4; ++i)
#pragma unroll
        for (int j = 0; j < 4; ++j)
          acc[i][j] = __builtin_amdgcn_mfma_f32_16x16x32_bf16(bfr[j], af[i], acc[i][j], 0, 0, 0);
    }
  }

  if (isV) {  // V -> [b,h,d,k], 4 consecutive k per 8B store
#pragma unroll
    for (int i = 0; i < 4; ++i) {
      int gmb = m0 + wm + i * 16 + quad * 4;
      int b = gmb >> 11, kp = gmb & 2047;
#pragma unroll
      for (int j = 0; j < 4; ++j) {
        int gn = n0 + wn + j * 16 + l15;
        int h = (gn >> 6) & 15, d = gn & 63;
        us4 pk;
#pragma unroll
        for (int r = 0; r < 4; ++r) pk[r] = b2u(acc[i][j][r]);
        *(us4*)(Vt + ((((size_t)b * 16 + h) * 64 + d) << 11) + kp) = pk;
      }
    }
    return;
  }
  // Q/K swapped epilogue: gm = ..+l15 (s), gn = ..+quad*4+r (d packed)
  const float scale = isQ ? LOG2E : 1.0f;
  bf16* dst = isQ ? Qb : Kb;
#pragma unroll
  for (int i = 0; i < 4; ++i) {
    int gm = m0 + wm + i * 16 + l15;
    int b = gm >> 11, s = gm & 2047;
#pragma unroll
    for (int j = 0; j < 4; ++j) {
      int gn = n0 + wn + j * 16 + quad * 4;
      int h = (gn >> 6) & 15, d0 = gn & 63;
      us4 pk;
#pragma unroll
      for (int r = 0; r < 4; ++r) pk[r] = b2u(acc[i][j][r] * scale);
      *(us4*)(dst + ((((size_t)b * 16 + h) * 2048 + s) << 6) + d0) = pk;
    }
  }
}

// ---------------- O projection: out[4096][1024] = Ob * WoT^T, 128x64 tiles ----------------
// pure async16 (verified r0-r4/r10/r12); swapped-operand MFMA -> float4 stores
__global__ __launch_bounds__(256) void gemm_o_k(const bf16* __restrict__ A,
                                                const bf16* __restrict__ Bt,
                                                float* __restrict__ C0) {
  __shared__ __align__(16) bf16 As[128 * 32];
  __shared__ __align__(16) bf16 Bs[64 * 32];
  const int tid = threadIdx.x;
  const int lane = tid & 63;
  const int w = tid >> 6;
  const int wm = w * 32;
  const int m0 = blockIdx.x * 128;
  const int n0 = blockIdx.y * 64;
  const int l15 = lane & 15;
  const int quad = lane >> 4;
  const int srow = lane >> 2;
  const int skg = lane & 3;

  f32x4 acc[2][4];
#pragma unroll
  for (int i = 0; i < 2; ++i)
#pragma unroll
    for (int j = 0; j < 4; ++j) acc[i][j] = (f32x4){0.f, 0.f, 0.f, 0.f};

  for (int k0 = 0; k0 < 1024; k0 += 32) {
    __syncthreads();
#pragma unroll
    for (int rep = 0; rep < 2; ++rep) {
      int seg = w * 2 + rep;
      async16(A + (size_t)(m0 + seg * 16 + srow) * 1024 + k0 + skg * 8, As + seg * 512);
    }
    async16(Bt + (size_t)(n0 + w * 16 + srow) * 1024 + k0 + skg * 8, Bs + w * 512);
    __syncthreads();
    bf16x8 af[2], bfr[4];
#pragma unroll
    for (int i = 0; i < 2; ++i)
      af[i] = *(const bf16x8*)(As + (wm + i * 16 + l15) * 32 + quad * 8);
#pragma unroll
    for (int j = 0; j < 4; ++j)
      bfr[j] = *(const bf16x8*)(Bs + (j * 16 + l15) * 32 + quad * 8);
#pragma unroll
    for (int i = 0; i < 2; ++i)
#pragma unroll
      for (int j = 0; j < 4; ++j)
        acc[i][j] = __builtin_amdgcn_mfma_f32_16x16x32_bf16(bfr[j], af[i], acc[i][j], 0, 0, 0);
  }
#pragma unroll
  for (int i = 0; i < 2; ++i) {
    int gm = m0 + wm + i * 16 + l15;
#pragma unroll
    for (int j = 0; j < 4; ++j) {
      int gn = n0 + j * 16 + quad * 4;
      *(f32x4*)(C0 + (size_t)gm * 1024 + gn) = acc[i][j];
    }
  }
}

// ---------------- fused attention, transposed-S, streamed softmax, NO max tracking ----------------
// Best measured configuration (r12: 60.2 us, 60 VGPR, 36% occ, FETCH 12.6 MB).
// XCD swizzle: wg = xcd + 8*slot; bh = xcd*4 + slot>>4, qt = slot&15 -> one
// bh's 16 q-tiles on ONE XCD, K/V L2-resident.
// 8 waves / 512 threads: waves 0-3 (kg=0) even 128-k tiles, waves 4-7 (kg=1)
// odd tiles, private Ks/Vs per group (padded strides, 2-way banks = free).
// Softmax uses FIXED m=0 (scores bounded ~|25|; exact for any consistent m).
// Group 1 dumps (l,O) to LDS; group 0 merges: O=(O0+O1)/(l0+l1).
// LDS: lbias[2176]f32 | Ks[2][128*STK] | Vs[2][64*SVK] = 78336 B (2 blocks/CU).
#define STK 68
#define SVK 136
#define KS_OFF 8704
#define VS_OFF 43520
__global__ __launch_bounds__(512, 2) void attn_k(const bf16* __restrict__ Qb,
                                                 const bf16* __restrict__ Kb,
                                                 const bf16* __restrict__ Vt,
                                                 const float* __restrict__ lut,
                                                 bf16* __restrict__ Ob) {
  __shared__ __align__(16) char smem[78336];
  float* lbias = (float*)smem;
  bf16* Ksb = (bf16*)(smem + KS_OFF);  // [2][128*STK]
  bf16* Vsb = (bf16*)(smem + VS_OFF);  // [2][64*SVK]

  const int tid = threadIdx.x;
  const int lane = tid & 63;
  const int w = tid >> 6;    // 0..7
  const int wq = w & 3;      // q-strip within block
  const int kg = w >> 2;     // k-group: 0 = even tiles, 1 = odd tiles
  const int t256 = tid & 255;
  const int q31 = lane & 31;
  const int half = lane >> 5;

  bf16* Ks = Ksb + kg * (128 * STK);
  bf16* Vs = Vsb + kg * (64 * SVK);

  // XCD swizzle: wg = xcd + 8*slot (HW round-robin wg->XCD assumption)
  const int wg = blockIdx.x;        // 0..511
  const int xcd = wg & 7;
  const int slot = wg >> 3;         // 0..63
  const int bh = xcd * 4 + (slot >> 4);  // 0..31
  const int qt = slot & 15;              // 0..15
  const int h = bh & 15, b = bh >> 4;
  const int qb = qt * 128;

  const int gbase = h * 4096 + 1921 - qb;
  for (int t = tid; t < 2175; t += 512) lbias[t] = lut[gbase + t];

  const size_t base = (size_t)bh * 2048 * 64;   // Qb/Kb rows
  const size_t vbase = (size_t)bh * 64 * 2048;  // Vt rows
  const int qg = qb + wq * 32 + q31;

  // Q B-frags (pre-scaled by log2e in projection)
  bf16x8 qf[4];
#pragma unroll
  for (int c = 0; c < 4; ++c)
    qf[c] = *(const bf16x8*)(Qb + base + (size_t)qg * 64 + c * 16 + half * 8);

  f32x16 oacc[2];
#pragma unroll
  for (int dj = 0; dj < 2; ++dj)
#pragma unroll
    for (int r = 0; r < 16; ++r) oacc[dj][r] = 0.f;
  float l_run = 0.f;

  const int kt0 = kg * 128;  // group's first tile

  for (int it = 0; it < 8; ++it) {
    const int kt = it * 256 + kt0;  // this group's k-tile base
    __syncthreads();  // all waves done reading their Ks/Vs
    {  // stage: issue both K and V loads, one wait, write LDS (in-window)
      uint4 kr[4], vr[4];
#pragma unroll
      for (int rep = 0; rep < 4; ++rep) {
        int slot2 = t256 + rep * 256;
        kr[rep] = *(const uint4*)(Kb + base + (size_t)(kt + (slot2 >> 3)) * 64 + (slot2 & 7) * 8);
        vr[rep] = *(const uint4*)(Vt + vbase + (size_t)(slot2 >> 4) * 2048 + kt + (slot2 & 15) * 8);
      }
#pragma unroll
      for (int rep = 0; rep < 4; ++rep) {
        int slot2 = t256 + rep * 256;
        st16(Ks + (slot2 >> 3) * STK + (slot2 & 7) * 8, kr[rep]);
        st16(Vs + (slot2 >> 4) * SVK + (slot2 & 15) * 8, vr[rep]);
      }
    }
    __syncthreads();

    const int xbase = kt + 127 + 4 * half - wq * 32 - q31;
#pragma unroll
    for (int mt = 0; mt < 4; ++mt) {
      // S^T = K·Q^T for this 32-k mt-tile; bias pre-loaded in the accumulator
      f32x16 sacc;
#pragma unroll
      for (int a2 = 0; a2 < 4; ++a2)
#pragma unroll
        for (int rr = 0; rr < 4; ++rr)
          sacc[4 * a2 + rr] = lbias[xbase + mt * 32 + 8 * a2 + rr];
#pragma unroll
      for (int c = 0; c < 4; ++c) {
        bf16x8 kf = ld16(Ks + (mt * 32 + q31) * STK + c * 16 + half * 8);
        sacc = __builtin_amdgcn_mfma_f32_32x32x16_bf16(kf, qf[c], sacc, 0, 0, 0);
      }

      // exp (m=0, no subtract) + sum (4 parallel accumulators) + pack quads
      us4 ownq[4];
      f32x4 sv = (f32x4){0.f, 0.f, 0.f, 0.f};
#pragma unroll
      for (int a = 0; a < 4; ++a) {
        us4 pk;
#pragma unroll
        for (int rr = 0; rr < 4; ++rr) {
          float p = EXP2(sacc[4 * a + rr]);
          sv[rr] += p;
          pk[rr] = b2u_fast(p);
        }
        ownq[a] = pk;
      }
      l_run += (sv[0] + sv[1]) + (sv[2] + sv[3]);

      // exchange complementary k-quads across the half boundary (no LDS)
      us4 rcv0 = shfl32_us4(half ? ownq[0] : ownq[1]);
      us4 rcv1 = shfl32_us4(half ? ownq[2] : ownq[3]);

      // O^T += V^T·P^T for this mt's two 16-k chunks
#pragma unroll
      for (int p = 0; p < 2; ++p) {
        us4 rc = p ? rcv1 : rcv0;
        bf16x8 pfc = half ? mk8(rc, ownq[2 * p + 1]) : mk8(ownq[2 * p], rc);
#pragma unroll
        for (int dj = 0; dj < 2; ++dj) {
          bf16x8 vf = ld16(Vs + (dj * 32 + q31) * SVK + (mt * 2 + p) * 16 + half * 8);
          oacc[dj] = __builtin_amdgcn_mfma_f32_32x32x16_bf16(vf, pfc, oacc[dj], 0, 0, 0);
        }
      }
    }
  }

  // pair-sum of l (one shfl at the end)
  l_run += __shfl_xor(l_run, 32);

  // ---- merge the two k-groups (group 1 -> LDS -> group 0 combines) ----
  __syncthreads();  // everyone done with Ks/Vs/lbias
  float* mbuf = (float*)smem;  // 4 waves * 64 lanes * 35 f32 = 35840 B (< 78336)
  if (kg) {
    float* p = mbuf + ((size_t)(wq * 64 + lane)) * 35;  // stride 35: 2-way banks, free
    p[0] = l_run;
#pragma unroll
    for (int dj = 0; dj < 2; ++dj)
#pragma unroll
      for (int r = 0; r < 16; ++r) p[1 + dj * 16 + r] = oacc[dj][r];
  }
  __syncthreads();
  if (kg) return;

  const float* p = mbuf + ((size_t)(wq * 64 + lane)) * 35;
  float inv = 1.0f / (l_run + p[0]);

  // epilogue: O[qg][d] = (O0+O1)/(l0+l1), 8B packed stores
#pragma unroll
  for (int dj = 0; dj < 2; ++dj)
#pragma unroll
    for (int g = 0; g < 4; ++g) {
      us4 pk;
#pragma unroll
      for (int rr = 0; rr < 4; ++rr)
        pk[rr] = b2u((oacc[dj][4 * g + rr] + p[1 + dj * 16 + 4 * g + rr]) * inv);
      int d0 = dj * 32 + 8 * g + 4 * half;
      *(us4*)(Ob + ((size_t)(b * 2048 + qg)) * 1024 + h * 64 + d0) = pk;
    }
}

// ---------------- launch ----------------
extern "C" void kernel_launch(void* const* d_in, const int* in_sizes, int n_in,
                              void* d_out, int out_size, void* d_ws, size_t ws_size,
                              hipStream_t stream) {
  const float* hidden = (const float*)d_in[0];
  const float* kvs    = (const float*)d_in[1];
  const float* Wq     = (const float*)d_in[2];
  const float* Wkv    = (const float*)d_in[3];
  const float* Wo     = (const float*)d_in[4];
  const float* relb   = (const float*)d_in[5];
  float* out = (float*)d_out;

  char* ws = (char*)d_ws;
  bf16* WqT  = (bf16*)(ws + (size_t)0);           // 2 MB
  bf16* WkvT = (bf16*)(ws + ((size_t)2 << 20));   // 4 MB
  bf16* WoT  = (bf16*)(ws + ((size_t)6 << 20));   // 2 MB
  bf16* Ob   = (bf16*)(ws + ((size_t)8 << 20));   // 8 MB [B,S,E]
  bf16* hbf  = Ob;                                //   aliased: dead after gemm_qkv
  bf16* Qb   = (bf16*)(ws + ((size_t)16 << 20));  // 8 MB [B,H,S,D]
  bf16* Kb   = (bf16*)(ws + ((size_t)24 << 20));  // 8 MB [B,H,K,D]
  bf16* Vt   = (bf16*)(ws + ((size_t)32 << 20));  // 8 MB [B,H,D,K]
  float* LUT = (float*)(ws + ((size_t)40 << 20)); // 256 KB
  bf16* kbf  = (bf16*)d_out;                      // 8 MB scratch in d_out, overwritten by gemm_o

  // weights transpose+cast + bias LUT, one launch
  prep_k<<<dim3(64, 32, 4), dim3(32, 8), 0, stream>>>(Wq, Wkv, Wo, relb, WqT, WkvT, WoT, LUT);
  // inputs fp32 -> bf16 (HBM-bound, ~11 us; buys async16 staging in gemm_qkv)
  cast2_k<<<4096, 256, 0, stream>>>(hidden, kvs, hbf, kbf);
  // Q (x log2e), K, V projections
  gemm_qkv_k<<<dim3(32, 24), 256, 0, stream>>>(hbf, kbf, WqT, WkvT, Qb, Kb, Vt);
  // attention -> Ob (overwrites hbf region, safe: hbf consumed); 1D grid, XCD-swizzled
  attn_k<<<dim3(512), 512, 0, stream>>>(Qb, Kb, Vt, LUT, Ob);
  // out = Ob @ Wo (overwrites kbf region, safe: kbf consumed)
  gemm_o_k<<<dim3(32, 16), 256, 0, stream>>>(Ob, WoT, out);
}